// Round 1
// baseline (310.077 us; speedup 1.0000x reference)
//
#include <hip/hip_runtime.h>
#include <stdint.h>

#define BATCH 64
#define TLEN 1024
#define FDIM 1024

// Monotonic float->uint32 encoding: enc(a) > enc(b) iff a > b (no NaNs here).
__device__ __forceinline__ uint32_t fenc(float f) {
    uint32_t u = __float_as_uint(f);
    return (u & 0x80000000u) ? ~u : (u | 0x80000000u);
}

// Butterfly max across the 64-lane wave; every lane ends with the max.
__device__ __forceinline__ unsigned long long wave_max_u64(unsigned long long v) {
#pragma unroll
    for (int off = 32; off > 0; off >>= 1) {
        unsigned long long o = __shfl_xor(v, off, 64);
        if (o > v) v = o;
    }
    return v;
}

// One wave per batch. Computes all selections, writes 16 gather indices per
// batch to idx_ws:
//   slot 0      : hard normal (1)
//   slots 1..3  : hard abnormal (3, in top-k order)
//   slots 4..5  : confident normal (2)
//   slots 6..15 : confident abnormal (10)
__global__ __launch_bounds__(64) void select_kernel(
    const float* __restrict__ rgb, const float* __restrict__ flow,
    int* __restrict__ idx_ws)
{
    const int b = blockIdx.x;
    const unsigned lane = threadIdx.x;
    const float* s = rgb + b * TLEN;

    // Each lane owns 16 candidates: t = lane + 64*j
    unsigned long long khard[16], kabn[16], knor[16];
#pragma unroll
    for (int j = 0; j < 16; ++j) {
        unsigned t = lane + 64u * j;
        float x = s[t];
        unsigned low = ~t;  // larger low <=> smaller index (tie-break: lower idx wins)
        khard[j] = ((unsigned long long)fenc(-fabsf(x - 0.5f)) << 32) | low;
        kabn[j]  = ((unsigned long long)fenc(x) << 32) | low;
        knor[j]  = ((unsigned long long)fenc(-x) << 32) | low;
    }

    // ---- hard top-10 (closest to 0.5) ----
    int hard_idx[10];
#pragma unroll
    for (int i = 0; i < 10; ++i) {
        unsigned long long m = 0;
#pragma unroll
        for (int j = 0; j < 16; ++j) if (khard[j] > m) m = khard[j];
        unsigned long long w = wave_max_u64(m);
        unsigned t = ~(unsigned)(w & 0xFFFFFFFFull);
        hard_idx[i] = (int)t;
        if ((t & 63u) == lane) khard[t >> 6] = 0;  // mask winner
    }

    // ---- hard_flow (uniform scalar loads, same for all lanes) ----
    float hf[10];
#pragma unroll
    for (int k = 0; k < 10; ++k) hf[k] = flow[b * TLEN + hard_idx[k]];

    // top-3 of hard_flow (value desc, tie -> lower k), with masking
    int abn[3];
    int used = 0;
#pragma unroll
    for (int i = 0; i < 3; ++i) {
        int best = -1; float bv = 0.0f;
#pragma unroll
        for (int k = 0; k < 10; ++k) {
            bool avail = !(used & (1 << k));
            if (avail && (best < 0 || hf[k] > bv)) { best = k; bv = hf[k]; }
        }
        abn[i] = best; used |= (1 << best);
    }
    // bottom-1 of hard_flow (min, tie -> lower k); NOT excluding abn picks
    int nor = 0; float nv = hf[0];
#pragma unroll
    for (int k = 1; k < 10; ++k) { if (hf[k] < nv) { nv = hf[k]; nor = k; } }

    // ---- confident normal: 2 smallest rgb ----
    int conf_nor[2];
#pragma unroll
    for (int i = 0; i < 2; ++i) {
        unsigned long long m = 0;
#pragma unroll
        for (int j = 0; j < 16; ++j) if (knor[j] > m) m = knor[j];
        unsigned long long w = wave_max_u64(m);
        unsigned t = ~(unsigned)(w & 0xFFFFFFFFull);
        conf_nor[i] = (int)t;
        if ((t & 63u) == lane) knor[t >> 6] = 0;
    }

    // ---- confident abnormal: 10 largest rgb ----
    int conf_abn[10];
#pragma unroll
    for (int i = 0; i < 10; ++i) {
        unsigned long long m = 0;
#pragma unroll
        for (int j = 0; j < 16; ++j) if (kabn[j] > m) m = kabn[j];
        unsigned long long w = wave_max_u64(m);
        unsigned t = ~(unsigned)(w & 0xFFFFFFFFull);
        conf_abn[i] = (int)t;
        if ((t & 63u) == lane) kabn[t >> 6] = 0;
    }

    if (lane == 0) {
        int* o = idx_ws + b * 16;
        o[0] = hard_idx[nor];
        o[1] = hard_idx[abn[0]];
        o[2] = hard_idx[abn[1]];
        o[3] = hard_idx[abn[2]];
        o[4] = conf_nor[0];
        o[5] = conf_nor[1];
#pragma unroll
        for (int k = 0; k < 10; ++k) o[6 + k] = conf_abn[k];
    }
}

// One block per output row (64 batches * 16 rows). 256 threads x float4 = 1024 f32.
// Output layout (rows of FDIM floats):
//   rows [0,64)    : hard_feat_nor  [B,1,F]
//   rows [64,256)  : hard_feat_abn  [B,3,F]
//   rows [256,384) : conf_rgb_feat_nor [B,2,F]
//   rows [384,1024): conf_rgb_feat_abn [B,10,F]
__global__ __launch_bounds__(256) void gather_kernel(
    const float* __restrict__ feat, const int* __restrict__ idx_ws,
    float* __restrict__ out)
{
    const int row = blockIdx.x;       // 0..1023
    const int b = row >> 4;
    const int slot = row & 15;
    const int t = idx_ws[row];

    const float4* src = (const float4*)(feat + ((size_t)b * TLEN + t) * FDIM);

    size_t drow;
    if (slot == 0)       drow = (size_t)b;
    else if (slot <= 3)  drow = (size_t)(64 + b * 3 + (slot - 1));
    else if (slot <= 5)  drow = (size_t)(256 + b * 2 + (slot - 4));
    else                 drow = (size_t)(384 + b * 10 + (slot - 6));

    float4* dst = (float4*)(out + drow * FDIM);
    dst[threadIdx.x] = src[threadIdx.x];
}

extern "C" void kernel_launch(void* const* d_in, const int* in_sizes, int n_in,
                              void* d_out, int out_size, void* d_ws, size_t ws_size,
                              hipStream_t stream) {
    const float* feat  = (const float*)d_in[0];   // [64,1024,1024] f32
    const float* s_rgb = (const float*)d_in[1];   // [64,1024] f32
    const float* s_flw = (const float*)d_in[2];   // [64,1024] f32
    float* out = (float*)d_out;                   // 1,048,576 f32
    int* idx_ws = (int*)d_ws;                     // 1024 ints

    select_kernel<<<BATCH, 64, 0, stream>>>(s_rgb, s_flw, idx_ws);
    gather_kernel<<<BATCH * 16, 256, 0, stream>>>(feat, idx_ws, out);
}

// Round 2
// 301.716 us; speedup vs baseline: 1.0277x; 1.0277x over previous
//
#include <hip/hip_runtime.h>
#include <stdint.h>

#define BATCH 64
#define TLEN 1024
#define FDIM 1024

// Monotonic float->uint32 encoding: enc(a) > enc(b) iff a > b (no NaNs here).
__device__ __forceinline__ uint32_t fenc(float f) {
    uint32_t u = __float_as_uint(f);
    return (u & 0x80000000u) ? ~u : (u | 0x80000000u);
}

// Butterfly max across the 64-lane wave; every lane ends with the max.
__device__ __forceinline__ unsigned long long wave_max_u64(unsigned long long v) {
#pragma unroll
    for (int off = 32; off > 0; off >>= 1) {
        unsigned long long o = __shfl_xor(v, off, 64);
        if (o > v) v = o;
    }
    return v;
}

// Iterative top-K over keys held 16/lane (key = (fenc(val)<<32) | ~t).
// Every lane ends with the full result list (wave-uniform).
template <int K>
__device__ __forceinline__ void topk_rounds(unsigned long long* keys,
                                            unsigned lane, int* out_idx) {
#pragma unroll
    for (int i = 0; i < K; ++i) {
        unsigned long long m = 0;
#pragma unroll
        for (int j = 0; j < 16; ++j) if (keys[j] > m) m = keys[j];
        unsigned long long w = wave_max_u64(m);
        unsigned t = ~(unsigned)(w & 0xFFFFFFFFull);
        out_idx[i] = (int)t;
        if ((t & 63u) == lane) keys[t >> 6] = 0;  // mask winner
    }
}

// One block (1024 threads, 16 waves) per batch.
// Waves 0..2 run the three independent selections in parallel, then the whole
// block gathers 16 feature rows.
// LDS slot layout:
//   0      : hard normal (1)
//   1..3   : hard abnormal (3)
//   4..5   : confident normal (2)
//   6..15  : confident abnormal (10)
__global__ __launch_bounds__(1024) void fused_kernel(
    const float* __restrict__ feat, const float* __restrict__ rgb,
    const float* __restrict__ flow, float* __restrict__ out)
{
    __shared__ int sidx[16];
    const int b = blockIdx.x;
    const unsigned tid = threadIdx.x;
    const unsigned lane = tid & 63u;
    const unsigned wave = tid >> 6;

    if (wave < 3) {
        const float* s = rgb + b * TLEN;
        unsigned long long keys[16];
#pragma unroll
        for (int j = 0; j < 16; ++j) {
            unsigned t = lane + 64u * j;
            float x = s[t];
            float v = (wave == 0) ? -fabsf(x - 0.5f) : (wave == 1) ? x : -x;
            keys[j] = ((unsigned long long)fenc(v) << 32) | (unsigned)(~t);
        }

        if (wave == 0) {
            // hard top-10 (closest to 0.5), then flow-based top3/bottom1
            int hard_idx[10];
            topk_rounds<10>(keys, lane, hard_idx);
            float hf[10];
#pragma unroll
            for (int k = 0; k < 10; ++k) hf[k] = flow[b * TLEN + hard_idx[k]];
            // top-3 of hard_flow (desc, tie -> lower k)
            int abn[3]; int used = 0;
#pragma unroll
            for (int i = 0; i < 3; ++i) {
                int best = -1; float bv = 0.0f;
#pragma unroll
                for (int k = 0; k < 10; ++k) {
                    bool avail = !(used & (1 << k));
                    if (avail && (best < 0 || hf[k] > bv)) { best = k; bv = hf[k]; }
                }
                abn[i] = best; used |= (1 << best);
            }
            // bottom-1 of hard_flow (min, tie -> lower k)
            int nor = 0; float nv = hf[0];
#pragma unroll
            for (int k = 1; k < 10; ++k) if (hf[k] < nv) { nv = hf[k]; nor = k; }
            if (lane == 0) {
                sidx[0] = hard_idx[nor];
                sidx[1] = hard_idx[abn[0]];
                sidx[2] = hard_idx[abn[1]];
                sidx[3] = hard_idx[abn[2]];
            }
        } else if (wave == 1) {
            // confident abnormal: 10 largest rgb
            int ca[10];
            topk_rounds<10>(keys, lane, ca);
            if (lane == 0) {
#pragma unroll
                for (int k = 0; k < 10; ++k) sidx[6 + k] = ca[k];
            }
        } else {
            // confident normal: 2 smallest rgb
            int cn[2];
            topk_rounds<2>(keys, lane, cn);
            if (lane == 0) { sidx[4] = cn[0]; sidx[5] = cn[1]; }
        }
    }
    __syncthreads();

    // Gather: 16 rows x 256 float4. Quarter q of the block handles slots
    // 4q..4q+3; each thread copies one float4 per slot (coalesced).
    const unsigned q = tid >> 8;    // 0..3
    const unsigned c = tid & 255u;  // float4 column within row
#pragma unroll
    for (int s = 0; s < 4; ++s) {
        const int slot = (int)q * 4 + s;
        const int t = sidx[slot];
        const float4* src =
            (const float4*)(feat + ((size_t)b * TLEN + t) * FDIM);
        size_t drow;
        if (slot == 0)       drow = (size_t)b;                       // [B,1,F]
        else if (slot <= 3)  drow = (size_t)(64 + b * 3 + (slot - 1));   // [B,3,F]
        else if (slot <= 5)  drow = (size_t)(256 + b * 2 + (slot - 4));  // [B,2,F]
        else                 drow = (size_t)(384 + b * 10 + (slot - 6)); // [B,10,F]
        ((float4*)(out + drow * FDIM))[c] = src[c];
    }
}

extern "C" void kernel_launch(void* const* d_in, const int* in_sizes, int n_in,
                              void* d_out, int out_size, void* d_ws, size_t ws_size,
                              hipStream_t stream) {
    const float* feat  = (const float*)d_in[0];   // [64,1024,1024] f32
    const float* s_rgb = (const float*)d_in[1];   // [64,1024] f32
    const float* s_flw = (const float*)d_in[2];   // [64,1024] f32
    float* out = (float*)d_out;                   // 1,048,576 f32

    fused_kernel<<<BATCH, 1024, 0, stream>>>(feat, s_rgb, s_flw, out);
}